// Round 9
// baseline (837.713 us; speedup 1.0000x reference)
//
#include <hip/hip_runtime.h>

// ---------------------------------------------------------------------------
// MHSA (faithful: softmax over HEADS at each position).
//   cvt_all: q,k,v,Wq..Wo fp32->bf16 (one launch)
//   GEMM: 256x256 tile, 8 waves, BK=32, 4-buffer ring (T+3 prefetch),
//         2 phases/tile, vmcnt(8)/tile, row-pair XOR swizzle,
//         *** mfma_f32_32x32x16_bf16 *** (half the issue slots of 16x16x32)
//   attention: per-position 16x16 softmax-over-heads + PV, permuted scatter
// ---------------------------------------------------------------------------

#define DEV __device__ __forceinline__

using short8  = __attribute__((ext_vector_type(8))) short;
using ushort8 = __attribute__((ext_vector_type(8))) unsigned short;
using f32x4   = __attribute__((ext_vector_type(4))) float;
using f32x16  = __attribute__((ext_vector_type(16))) float;
using u16x8   = __attribute__((ext_vector_type(8))) unsigned short;

constexpr int BATCH = 4, SEQ = 4096, DIM = 2048;
constexpr int GM = BATCH * SEQ;   // 16384
constexpr int GN = DIM, GK = DIM; // 2048

DEV unsigned short f2bf(float f) {
  unsigned int u = __builtin_bit_cast(unsigned int, f);
  u += 0x7FFFu + ((u >> 16) & 1u);   // RNE
  return (unsigned short)(u >> 16);
}
DEV float bf2f(unsigned short h) {
  unsigned int u = ((unsigned int)h) << 16;
  return __builtin_bit_cast(float, u);
}

DEV void gload16(const void* g, void* l) {
  __builtin_amdgcn_global_load_lds(
      (const __attribute__((address_space(1))) void*)g,
      (__attribute__((address_space(3))) void*)l, 16, 0, 0);
}

#define BAR    __builtin_amdgcn_s_barrier()
#define LGKM0  asm volatile("s_waitcnt lgkmcnt(0)" ::: "memory")
#define VMC(N) asm volatile("s_waitcnt vmcnt(" #N ")" ::: "memory")
#define SCHED0 __builtin_amdgcn_sched_barrier(0)
#define PRIO1  __builtin_amdgcn_s_setprio(1)
#define PRIO0  __builtin_amdgcn_s_setprio(0)
#define MFMA32(a, b, c) __builtin_amdgcn_mfma_f32_32x32x16_bf16(a, b, c, 0, 0, 0)

constexpr size_t NE_C = (size_t)GM * GK;   // 33,554,432
constexpr size_t WE_C = (size_t)GK * GN;   //  4,194,304

// ---------------- fused fp32 -> bf16 conversion (7 tensors, 1 launch) -----
__global__ __launch_bounds__(256)
void cvt_all(const float* __restrict__ q, const float* __restrict__ k,
             const float* __restrict__ v, const float* __restrict__ Wq,
             const float* __restrict__ Wk, const float* __restrict__ Wv,
             const float* __restrict__ Wo,
             unsigned short* __restrict__ Qin, unsigned short* __restrict__ Kin,
             unsigned short* __restrict__ Vin, unsigned short* __restrict__ Wqb,
             unsigned short* __restrict__ Wkb, unsigned short* __restrict__ Wvb,
             unsigned short* __restrict__ Wob) {
  size_t gi = ((size_t)blockIdx.x * 256 + threadIdx.x) * 8;
  const float* src;
  unsigned short* dst;
  size_t off;
  if (gi < NE_C)            { src = q;  dst = Qin; off = gi; }
  else if (gi < 2 * NE_C)   { src = k;  dst = Kin; off = gi - NE_C; }
  else if (gi < 3 * NE_C)   { src = v;  dst = Vin; off = gi - 2 * NE_C; }
  else {
    size_t w = gi - 3 * NE_C;
    if (w < WE_C)           { src = Wq; dst = Wqb; off = w; }
    else if (w < 2 * WE_C)  { src = Wk; dst = Wkb; off = w - WE_C; }
    else if (w < 3 * WE_C)  { src = Wv; dst = Wvb; off = w - 2 * WE_C; }
    else                    { src = Wo; dst = Wob; off = w - 3 * WE_C; }
  }
  f32x4 f0 = *(const f32x4*)(src + off);
  f32x4 f1 = *(const f32x4*)(src + off + 4);
  ushort8 o;
#pragma unroll
  for (int j = 0; j < 4; ++j) { o[j] = f2bf(f0[j]); o[4 + j] = f2bf(f1[j]); }
  *(ushort8*)(dst + off) = o;
}

// ---------------- 256^2 8-wave BK=32 ring GEMM, 32x32x16 MFMA -------------
// LDS: As/Bs[4][256x32] bf16 = 128 KiB. Row-pair swizzle (proven 0-conflict):
//   addr(row,cb) = (row>>1)*128 + ((((row&1)<<6)|cb) ^ (((row>>1)&7)<<4))
// Wave (wm,wn): rows wm*128+mf*32, cols wn*64+nf*32 (mf 0-3, nf 0-1).
// Frag (row0,ks): lane reads 16B at row=row0+(lane&31), cb=ks*32+(lane>>5)*16
//   -> bank-slot (4(row&1)+2ks+hi)^((row>>1)&7) uniform -> free 2-way.
// Per tile T: P0 {rd af01(4)+bf(4); stage A(T+3); BAR; lgkm0; 8 MFMA; BAR}
//             P1 {rd af23(4); stage B(T+3); vmc(8|4|0); BAR; lgkm0; 8 MFMA; BAR}
template <bool OUTF32, bool MULTI>
__global__ __launch_bounds__(512, 2)
void gemm_d(const unsigned short* __restrict__ A0,
            const unsigned short* __restrict__ A1,
            const unsigned short* __restrict__ A2,
            const unsigned short* __restrict__ B0,
            const unsigned short* __restrict__ B1,
            const unsigned short* __restrict__ B2,
            const float* __restrict__ bi0, const float* __restrict__ bi1,
            const float* __restrict__ bi2,
            void* __restrict__ C0, void* __restrict__ C1,
            void* __restrict__ C2) {
  constexpr int BK = 32, KT = GK / BK;   // 64 K-tiles
  __shared__ unsigned short As[4][256 * BK];
  __shared__ unsigned short Bs[4][256 * BK];

  const int tid  = threadIdx.x;
  const int lane = tid & 63;
  const int wv   = tid >> 6;
  const int wm   = wv >> 2, wn = wv & 3;

  const int bid = (int)blockIdx.x;
  const int xcd = bid & 7, rr = bid >> 3;
  const int tens = MULTI ? (rr >> 6) : 0;
  const int r2 = MULTI ? (rr & 63) : rr;
  const int gg = r2 >> 5, jj = r2 & 31;
  const int mt = xcd * 8 + gg * 4 + (jj & 3);
  const int nt = jj >> 2;
  const int bm0 = mt * 256, bn0 = nt * 256;

  const unsigned short* Ap = tens == 0 ? A0 : tens == 1 ? A1 : A2;
  const unsigned short* Bp = tens == 0 ? B0 : tens == 1 ? B1 : B2;
  const float* bias        = tens == 0 ? bi0 : tens == 1 ? bi1 : bi2;
  void* Cp                 = tens == 0 ? C0 : tens == 1 ? C1 : C2;

  // staging: dest byte d (linear in 16KB tile) -> source (row, colbyte)
  int offA[2], offB[2];
#pragma unroll
  for (int r = 0; r < 2; ++r) {
    int d = tid * 16 + r * 8192;
    int line = d >> 7;
    int qq = (d & 127) ^ ((line & 7) << 4);
    int row = line * 2 + (qq >> 6);
    int c = qq & 63;                 // byte within 64B row
    offA[r] = (bm0 + row) * GK + (c >> 1);
    offB[r] = (bn0 + row) * GK + (c >> 1);
  }

  const int r31 = lane & 31, hi = lane >> 5;

  f32x16 acc[4][2] = {};
  short8 af0[2][2], af1[2][2], bf[2][2];

  auto stage = [&](const unsigned short* P, void* lbase, int T, int* offs) {
#pragma unroll
    for (int r = 0; r < 2; ++r)
      gload16(P + (size_t)offs[r] + (size_t)T * BK,
              (char*)lbase + (tid * 16 + r * 8192));
  };
  auto frag = [&](const unsigned short* lbase, int row0, int ks) -> short8 {
    int row = row0 + r31;
    int line = row >> 1;
    int cb = ks * 32 + hi * 16;
    int ad = line * 128 + ((((row & 1) << 6) + cb) ^ ((line & 7) << 4));
    return *(const short8*)((const char*)lbase + ad);
  };

  // ---- prologue: stage tiles 0,1,2 ----
  stage(Ap, &As[0][0], 0, offA); stage(Bp, &Bs[0][0], 0, offB);
  stage(Ap, &As[1][0], 1, offA); stage(Bp, &Bs[1][0], 1, offB);
  stage(Ap, &As[2][0], 2, offA); stage(Bp, &Bs[2][0], 2, offB);
  VMC(8);   // tile0 resident; tiles 1,2 in flight
  BAR;

  for (int T = 0; T < KT; ++T) {
    const int buf = T & 3, nxt = (T + 3) & 3;
    const unsigned short* Ab = &As[buf][0];
    const unsigned short* Bb = &Bs[buf][0];
    const bool pf = (T + 3 < KT);

    // ===== P0: mf0-1 x nf0-1 =====
#pragma unroll
    for (int mf = 0; mf < 2; ++mf)
#pragma unroll
      for (int ks = 0; ks < 2; ++ks)
        af0[mf][ks] = frag(Ab, wm * 128 + mf * 32, ks);
#pragma unroll
    for (int nf = 0; nf < 2; ++nf)
#pragma unroll
      for (int ks = 0; ks < 2; ++ks)
        bf[nf][ks] = frag(Bb, wn * 64 + nf * 32, ks);
    SCHED0;
    if (pf) stage(Ap, &As[nxt][0], T + 3, offA);
    SCHED0; BAR; LGKM0; SCHED0;
    PRIO1;
#pragma unroll
    for (int mf = 0; mf < 2; ++mf)
#pragma unroll
      for (int nf = 0; nf < 2; ++nf) {
        acc[mf][nf] = MFMA32(af0[mf][0], bf[nf][0], acc[mf][nf]);
        acc[mf][nf] = MFMA32(af0[mf][1], bf[nf][1], acc[mf][nf]);
      }
    PRIO0; SCHED0; BAR;

    // ===== P1: mf2-3 x nf0-1 =====
#pragma unroll
    for (int mf = 0; mf < 2; ++mf)
#pragma unroll
      for (int ks = 0; ks < 2; ++ks)
        af1[mf][ks] = frag(Ab, wm * 128 + 64 + mf * 32, ks);
    SCHED0;
    if (pf) stage(Bp, &Bs[nxt][0], T + 3, offB);
    SCHED0;
    if (pf)                 { VMC(8); }   // drain tile T+1; keep T+2,T+3
    else if (T + 2 < KT)    { VMC(4); }   // drain T+1; keep T+2
    else                    { VMC(0); }
    SCHED0; BAR; LGKM0; SCHED0;
    PRIO1;
#pragma unroll
    for (int mf = 0; mf < 2; ++mf)
#pragma unroll
      for (int nf = 0; nf < 2; ++nf) {
        acc[2 + mf][nf] = MFMA32(af1[mf][0], bf[nf][0], acc[2 + mf][nf]);
        acc[2 + mf][nf] = MFMA32(af1[mf][1], bf[nf][1], acc[2 + mf][nf]);
      }
    PRIO0; SCHED0; BAR;
  }

  // ---- epilogue: 32x32 C layout col=lane&31, row=(reg&3)+8*(reg>>2)+4*hi --
  float bs2[2];
#pragma unroll
  for (int nf = 0; nf < 2; ++nf) bs2[nf] = bias[bn0 + wn * 64 + nf * 32 + r31];
#pragma unroll
  for (int mf = 0; mf < 4; ++mf)
#pragma unroll
    for (int nf = 0; nf < 2; ++nf) {
      const int col = bn0 + wn * 64 + nf * 32 + r31;
#pragma unroll
      for (int reg = 0; reg < 16; ++reg) {
        const int r = (reg & 3) + 8 * (reg >> 2) + 4 * hi;
        const size_t row = (size_t)bm0 + wm * 128 + mf * 32 + r;
        float v = acc[mf][nf][reg] + bs2[nf];
        if constexpr (OUTF32)
          ((float*)Cp)[row * GN + col] = v;
        else
          ((unsigned short*)Cp)[row * GN + col] = f2bf(v);
      }
    }
}

// ---------------- per-position attention (softmax over heads) -------------
__global__ __launch_bounds__(256)
void attn_kernel(const unsigned short* __restrict__ Qb,
                 const unsigned short* __restrict__ Kb,
                 const unsigned short* __restrict__ Vb,
                 float* __restrict__ attnOut,
                 unsigned short* __restrict__ X2) {
  __shared__ float qf[16 * 128];
  __shared__ float kf[16 * 132];
  __shared__ float vf[16 * 128];
  __shared__ float sc[256];

  const int t = threadIdx.x;
  const int p = blockIdx.x;
  const size_t rowoff = (size_t)p * DIM;

  {
    const int e = t * 8;
    u16x8 qv = *(const u16x8*)(Qb + rowoff + e);
    u16x8 kv = *(const u16x8*)(Kb + rowoff + e);
    u16x8 vv = *(const u16x8*)(Vb + rowoff + e);
    const int r = t >> 4, c = (t & 15) * 8;
#pragma unroll
    for (int j = 0; j < 8; ++j) qf[r * 128 + c + j] = bf2f(qv[j]);
#pragma unroll
    for (int j = 0; j < 8; ++j) kf[r * 132 + c + j] = bf2f(kv[j]);
#pragma unroll
    for (int j = 0; j < 8; ++j) vf[r * 128 + c + j] = bf2f(vv[j]);
  }
  __syncthreads();

  const int i = t >> 4, j = t & 15;
  float s = 0.f;
#pragma unroll
  for (int d4 = 0; d4 < 32; ++d4) {
    f32x4 q4 = *(const f32x4*)&qf[i * 128 + d4 * 4];
    f32x4 k4 = *(const f32x4*)&kf[j * 132 + d4 * 4];
    s = fmaf(q4[0], k4[0], fmaf(q4[1], k4[1], fmaf(q4[2], k4[2], fmaf(q4[3], k4[3], s))));
  }
  s *= 0.08838834764831845f;

  float mx = s;
#pragma unroll
  for (int off = 8; off; off >>= 1) mx = fmaxf(mx, __shfl_xor(mx, off, 16));
  float ex = __expf(s - mx);
  float sum = ex;
#pragma unroll
  for (int off = 8; off; off >>= 1) sum += __shfl_xor(sum, off, 16);
  float a = ex / sum;

  attnOut[(size_t)p * 256 + t] = a;
  sc[t] = a;
  __syncthreads();

  const int dh0 = j * 8;
  float o[8] = {};
#pragma unroll
  for (int jjq = 0; jjq < 16; ++jjq) {
    float aij = sc[i * 16 + jjq];
#pragma unroll
    for (int e2 = 0; e2 < 8; ++e2)
      o[e2] = fmaf(aij, vf[jjq * 128 + dh0 + e2], o[e2]);
  }
  const int b = p >> 12, spos = p & 4095;
  const int row = i * 256 + (spos >> 4);
  const int col = ((spos & 15) << 7) + dh0;
  ushort8 pk;
#pragma unroll
  for (int e2 = 0; e2 < 8; ++e2) pk[e2] = f2bf(o[e2]);
  *(ushort8*)(X2 + (size_t)b * (SEQ * DIM) + (size_t)row * DIM + col) = pk;
}

// ---------------------------------------------------------------------------
extern "C" void kernel_launch(void* const* d_in, const int* in_sizes, int n_in,
                              void* d_out, int out_size, void* d_ws,
                              size_t ws_size, hipStream_t stream) {
  const float* q  = (const float*)d_in[0];
  const float* k  = (const float*)d_in[1];
  const float* v  = (const float*)d_in[2];
  const float* Wq = (const float*)d_in[3];
  const float* bq = (const float*)d_in[4];
  const float* Wk = (const float*)d_in[5];
  const float* bk = (const float*)d_in[6];
  const float* Wv = (const float*)d_in[7];
  const float* bv = (const float*)d_in[8];
  const float* Wo = (const float*)d_in[9];
  const float* bo = (const float*)d_in[10];

  const size_t NE = NE_C, WE = WE_C;

  unsigned short* ws16 = (unsigned short*)d_ws;
  unsigned short* Wq_b = ws16;
  unsigned short* Wk_b = Wq_b + WE;
  unsigned short* Wv_b = Wk_b + WE;
  unsigned short* Wo_b = Wv_b + WE;
  unsigned short* Qb   = Wo_b + WE;
  unsigned short* Kb   = Qb + NE;
  unsigned short* Vb   = Kb + NE;
  unsigned short* X2   = Vb + NE;
  unsigned short* Qin  = X2 + NE;
  unsigned short* Kin  = Qin + NE;
  unsigned short* Vin  = Kin + NE;

  float* outMain = (float*)d_out;
  float* attnOut = outMain + (size_t)GM * GN;

  const int cvt_blocks = (int)((3 * NE + 4 * WE) / 8 / 256);   // 57344
  cvt_all<<<cvt_blocks, 256, 0, stream>>>(q, k, v, Wq, Wk, Wv, Wo,
                                          Qin, Kin, Vin, Wq_b, Wk_b, Wv_b, Wo_b);

  // merged Q/K/V projection: 3 x 512 blocks in one dispatch
  gemm_d<false, true><<<1536, 512, 0, stream>>>(
      Qin, Kin, Vin, Wq_b, Wk_b, Wv_b, bq, bk, bv, Qb, Kb, Vb);

  attn_kernel<<<GM, 256, 0, stream>>>(Qb, Kb, Vb, attnOut, X2);

  // output projection (fp32 out)
  gemm_d<true, false><<<512, 512, 0, stream>>>(
      X2, nullptr, nullptr, Wo_b, nullptr, nullptr, bo, nullptr, nullptr,
      outMain, nullptr, nullptr);
}

// Round 12
// 817.791 us; speedup vs baseline: 1.0244x; 1.0244x over previous
//
#include <hip/hip_runtime.h>

// ---------------------------------------------------------------------------
// MHSA (faithful: softmax over HEADS at each position).
//   cvt_all: q,k,v,Wq..Wo fp32->bf16 (one launch)
//   GEMM: 256x256 tile, 8 waves, BK=32, 4-BUFFER RING (deep prefetch: tile
//         T+3 staged during tile T -> ~3 tiles of HBM/LLC latency cover),
//         2 phases/tile, vmcnt(8) once per tile, row-pair XOR swizzle.
//   attention: per-position 16x16 softmax-over-heads + PV, permuted scatter
// (R8 configuration — measured best: 819 us, passed.)
// ---------------------------------------------------------------------------

#define DEV __device__ __forceinline__

using short8  = __attribute__((ext_vector_type(8))) short;
using ushort8 = __attribute__((ext_vector_type(8))) unsigned short;
using f32x4   = __attribute__((ext_vector_type(4))) float;
using u16x8   = __attribute__((ext_vector_type(8))) unsigned short;

constexpr int BATCH = 4, SEQ = 4096, DIM = 2048;
constexpr int GM = BATCH * SEQ;   // 16384
constexpr int GN = DIM, GK = DIM; // 2048

DEV unsigned short f2bf(float f) {
  unsigned int u = __builtin_bit_cast(unsigned int, f);
  u += 0x7FFFu + ((u >> 16) & 1u);   // RNE
  return (unsigned short)(u >> 16);
}
DEV float bf2f(unsigned short h) {
  unsigned int u = ((unsigned int)h) << 16;
  return __builtin_bit_cast(float, u);
}

DEV void gload16(const void* g, void* l) {
  __builtin_amdgcn_global_load_lds(
      (const __attribute__((address_space(1))) void*)g,
      (__attribute__((address_space(3))) void*)l, 16, 0, 0);
}

#define BAR    __builtin_amdgcn_s_barrier()
#define LGKM0  asm volatile("s_waitcnt lgkmcnt(0)" ::: "memory")
#define VMC(N) asm volatile("s_waitcnt vmcnt(" #N ")" ::: "memory")
#define SCHED0 __builtin_amdgcn_sched_barrier(0)
#define PRIO1  __builtin_amdgcn_s_setprio(1)
#define PRIO0  __builtin_amdgcn_s_setprio(0)
#define MFMA16(a, b, c) __builtin_amdgcn_mfma_f32_16x16x32_bf16(a, b, c, 0, 0, 0)

constexpr size_t NE_C = (size_t)GM * GK;   // 33,554,432
constexpr size_t WE_C = (size_t)GK * GN;   //  4,194,304

// ---------------- fused fp32 -> bf16 conversion (7 tensors, 1 launch) -----
__global__ __launch_bounds__(256)
void cvt_all(const float* __restrict__ q, const float* __restrict__ k,
             const float* __restrict__ v, const float* __restrict__ Wq,
             const float* __restrict__ Wk, const float* __restrict__ Wv,
             const float* __restrict__ Wo,
             unsigned short* __restrict__ Qin, unsigned short* __restrict__ Kin,
             unsigned short* __restrict__ Vin, unsigned short* __restrict__ Wqb,
             unsigned short* __restrict__ Wkb, unsigned short* __restrict__ Wvb,
             unsigned short* __restrict__ Wob) {
  size_t gi = ((size_t)blockIdx.x * 256 + threadIdx.x) * 8;
  const float* src;
  unsigned short* dst;
  size_t off;
  if (gi < NE_C)            { src = q;  dst = Qin; off = gi; }
  else if (gi < 2 * NE_C)   { src = k;  dst = Kin; off = gi - NE_C; }
  else if (gi < 3 * NE_C)   { src = v;  dst = Vin; off = gi - 2 * NE_C; }
  else {
    size_t w = gi - 3 * NE_C;
    if (w < WE_C)           { src = Wq; dst = Wqb; off = w; }
    else if (w < 2 * WE_C)  { src = Wk; dst = Wkb; off = w - WE_C; }
    else if (w < 3 * WE_C)  { src = Wv; dst = Wvb; off = w - 2 * WE_C; }
    else                    { src = Wo; dst = Wob; off = w - 3 * WE_C; }
  }
  f32x4 f0 = *(const f32x4*)(src + off);
  f32x4 f1 = *(const f32x4*)(src + off + 4);
  ushort8 o;
#pragma unroll
  for (int j = 0; j < 4; ++j) { o[j] = f2bf(f0[j]); o[4 + j] = f2bf(f1[j]); }
  *(ushort8*)(dst + off) = o;
}

// ---------------- 256^2 8-wave BK=32 4-buffer deep-prefetch GEMM ----------
// LDS: As/Bs[4][256x32] bf16 = 128 KiB total.
// Swizzle (64B rows, row-pair packing into 128B lines):
//   addr(row,cb) = (row>>1)*128 + ((((row&1)<<6)|cb) ^ (((row>>1)&7)<<4))
// Per tile T (2 phases):
//   P0: rd af_lo(4)+bf(4); stage A(T+3); BAR; lgkm0; 16 MFMA; BAR
//   P1: rd af_hi(4);       stage B(T+3); vmc(8|4|0); BAR; lgkm0; 16 MFMA; BAR
// vmcnt: 12 loads in flight (tiles T+1..T+3, 4 each); vmc(8) drains T+1 only.
template <bool OUTF32, bool MULTI>
__global__ __launch_bounds__(512, 2)
void gemm_d(const unsigned short* __restrict__ A0,
            const unsigned short* __restrict__ A1,
            const unsigned short* __restrict__ A2,
            const unsigned short* __restrict__ B0,
            const unsigned short* __restrict__ B1,
            const unsigned short* __restrict__ B2,
            const float* __restrict__ bi0, const float* __restrict__ bi1,
            const float* __restrict__ bi2,
            void* __restrict__ C0, void* __restrict__ C1,
            void* __restrict__ C2) {
  constexpr int BK = 32, KT = GK / BK;   // 64 K-tiles
  __shared__ unsigned short As[4][256 * BK];
  __shared__ unsigned short Bs[4][256 * BK];

  const int tid  = threadIdx.x;
  const int lane = tid & 63;
  const int wv   = tid >> 6;
  const int wm   = wv >> 2, wn = wv & 3;

  // XCD-chunked mapping; MULTI: rr>>6 selects tensor (Q/K/V)
  const int bid = (int)blockIdx.x;
  const int xcd = bid & 7, rr = bid >> 3;
  const int tens = MULTI ? (rr >> 6) : 0;
  const int r2 = MULTI ? (rr & 63) : rr;
  const int gg = r2 >> 5, jj = r2 & 31;
  const int mt = xcd * 8 + gg * 4 + (jj & 3);
  const int nt = jj >> 2;
  const int bm0 = mt * 256, bn0 = nt * 256;

  const unsigned short* Ap = tens == 0 ? A0 : tens == 1 ? A1 : A2;
  const unsigned short* Bp = tens == 0 ? B0 : tens == 1 ? B1 : B2;
  const float* bias        = tens == 0 ? bi0 : tens == 1 ? bi1 : bi2;
  void* Cp                 = tens == 0 ? C0 : tens == 1 ? C1 : C2;

  // staging: dest byte d (linear in 16KB tile) -> source (row, colbyte)
  int offA[2], offB[2];
#pragma unroll
  for (int r = 0; r < 2; ++r) {
    int d = tid * 16 + r * 8192;
    int line = d >> 7;
    int qq = (d & 127) ^ ((line & 7) << 4);
    int row = line * 2 + (qq >> 6);
    int c = qq & 63;                 // byte within 64B row
    offA[r] = (bm0 + row) * GK + (c >> 1);
    offB[r] = (bn0 + row) * GK + (c >> 1);
  }

  const int r16 = lane & 15;
  const int kb = (lane >> 4) * 16;   // byte col of this lane's 16B frag

  f32x4 acc[8][4] = {};
  short8 af[4], bf[4];

  auto stage = [&](const unsigned short* P, void* lbase, int T, int* offs) {
#pragma unroll
    for (int r = 0; r < 2; ++r)
      gload16(P + (size_t)offs[r] + (size_t)T * BK,
              (char*)lbase + (tid * 16 + r * 8192));
  };
  auto frag = [&](const unsigned short* lbase, int row) -> short8 {
    int line = row >> 1;
    int ad = line * 128 + ((((row & 1) << 6) + kb) ^ ((line & 7) << 4));
    return *(const short8*)((const char*)lbase + ad);
  };

  // ---- prologue: stage tiles 0,1,2 ----
  stage(Ap, &As[0][0], 0, offA); stage(Bp, &Bs[0][0], 0, offB);
  stage(Ap, &As[1][0], 1, offA); stage(Bp, &Bs[1][0], 1, offB);
  stage(Ap, &As[2][0], 2, offA); stage(Bp, &Bs[2][0], 2, offB);
  VMC(8);   // tile0 resident; tiles 1,2 in flight
  BAR;

  for (int T = 0; T < KT; ++T) {
    const int buf = T & 3, nxt = (T + 3) & 3;
    const unsigned short* Ab = &As[buf][0];
    const unsigned short* Bb = &Bs[buf][0];
    const bool pf = (T + 3 < KT);

    // ===== P0: Q(mlo, n0-3) =====
#pragma unroll
    for (int m = 0; m < 4; ++m) af[m] = frag(Ab, wm * 128 + m * 16 + r16);
#pragma unroll
    for (int n = 0; n < 4; ++n) bf[n] = frag(Bb, wn * 64 + n * 16 + r16);
    SCHED0;
    if (pf) stage(Ap, &As[nxt][0], T + 3, offA);
    SCHED0; BAR; LGKM0; SCHED0;
    PRIO1;
#pragma unroll
    for (int m = 0; m < 4; ++m)
#pragma unroll
      for (int n = 0; n < 4; ++n)
        acc[m][n] = MFMA16(af[m], bf[n], acc[m][n]);
    PRIO0; SCHED0; BAR;

    // ===== P1: Q(mhi, n0-3) =====
#pragma unroll
    for (int m = 0; m < 4; ++m) af[m] = frag(Ab, wm * 128 + 64 + m * 16 + r16);
    SCHED0;
    if (pf) stage(Bp, &Bs[nxt][0], T + 3, offB);
    SCHED0;
    if (pf)                 { VMC(8); }   // drain tile T+1; keep T+2,T+3
    else if (T + 2 < KT)    { VMC(4); }   // drain T+1; keep T+2
    else                    { VMC(0); }
    SCHED0; BAR; LGKM0; SCHED0;
    PRIO1;
#pragma unroll
    for (int m = 0; m < 4; ++m)
#pragma unroll
      for (int n = 0; n < 4; ++n)
        acc[4 + m][n] = MFMA16(af[m], bf[n], acc[4 + m][n]);
    PRIO0; SCHED0; BAR;
  }

  // ---- epilogue: C row=(lane>>4)*4+i, col=lane&15 (m89-verified) ----
  float bs[4];
#pragma unroll
  for (int n = 0; n < 4; ++n) bs[n] = bias[bn0 + wn * 64 + n * 16 + r16];
  const int rb = (lane >> 4) * 4;
#pragma unroll
  for (int m = 0; m < 8; ++m)
#pragma unroll
    for (int i = 0; i < 4; ++i) {
      const size_t row = (size_t)bm0 + wm * 128 + m * 16 + rb + i;
#pragma unroll
      for (int n = 0; n < 4; ++n) {
        const int col = bn0 + wn * 64 + n * 16 + r16;
        float v = acc[m][n][i] + bs[n];
        if constexpr (OUTF32)
          ((float*)Cp)[row * GN + col] = v;
        else
          ((unsigned short*)Cp)[row * GN + col] = f2bf(v);
      }
    }
}

// ---------------- per-position attention (softmax over heads) -------------
__global__ __launch_bounds__(256)
void attn_kernel(const unsigned short* __restrict__ Qb,
                 const unsigned short* __restrict__ Kb,
                 const unsigned short* __restrict__ Vb,
                 float* __restrict__ attnOut,
                 unsigned short* __restrict__ X2) {
  __shared__ float qf[16 * 128];
  __shared__ float kf[16 * 132];
  __shared__ float vf[16 * 128];
  __shared__ float sc[256];

  const int t = threadIdx.x;
  const int p = blockIdx.x;
  const size_t rowoff = (size_t)p * DIM;

  {
    const int e = t * 8;
    u16x8 qv = *(const u16x8*)(Qb + rowoff + e);
    u16x8 kv = *(const u16x8*)(Kb + rowoff + e);
    u16x8 vv = *(const u16x8*)(Vb + rowoff + e);
    const int r = t >> 4, c = (t & 15) * 8;
#pragma unroll
    for (int j = 0; j < 8; ++j) qf[r * 128 + c + j] = bf2f(qv[j]);
#pragma unroll
    for (int j = 0; j < 8; ++j) kf[r * 132 + c + j] = bf2f(kv[j]);
#pragma unroll
    for (int j = 0; j < 8; ++j) vf[r * 128 + c + j] = bf2f(vv[j]);
  }
  __syncthreads();

  const int i = t >> 4, j = t & 15;
  float s = 0.f;
#pragma unroll
  for (int d4 = 0; d4 < 32; ++d4) {
    f32x4 q4 = *(const f32x4*)&qf[i * 128 + d4 * 4];
    f32x4 k4 = *(const f32x4*)&kf[j * 132 + d4 * 4];
    s = fmaf(q4[0], k4[0], fmaf(q4[1], k4[1], fmaf(q4[2], k4[2], fmaf(q4[3], k4[3], s))));
  }
  s *= 0.08838834764831845f;

  float mx = s;
#pragma unroll
  for (int off = 8; off; off >>= 1) mx = fmaxf(mx, __shfl_xor(mx, off, 16));
  float ex = __expf(s - mx);
  float sum = ex;
#pragma unroll
  for (int off = 8; off; off >>= 1) sum += __shfl_xor(sum, off, 16);
  float a = ex / sum;

  attnOut[(size_t)p * 256 + t] = a;
  sc[t] = a;
  __syncthreads();

  const int dh0 = j * 8;
  float o[8] = {};
#pragma unroll
  for (int jjq = 0; jjq < 16; ++jjq) {
    float aij = sc[i * 16 + jjq];
#pragma unroll
    for (int e2 = 0; e2 < 8; ++e2)
      o[e2] = fmaf(aij, vf[jjq * 128 + dh0 + e2], o[e2]);
  }
  const int b = p >> 12, spos = p & 4095;
  const int row = i * 256 + (spos >> 4);
  const int col = ((spos & 15) << 7) + dh0;
  ushort8 pk;
#pragma unroll
  for (int e2 = 0; e2 < 8; ++e2) pk[e2] = f2bf(o[e2]);
  *(ushort8*)(X2 + (size_t)b * (SEQ * DIM) + (size_t)row * DIM + col) = pk;
}

// ---------------------------------------------------------------------------
extern "C" void kernel_launch(void* const* d_in, const int* in_sizes, int n_in,
                              void* d_out, int out_size, void* d_ws,
                              size_t ws_size, hipStream_t stream) {
  const float* q  = (const float*)d_in[0];
  const float* k  = (const float*)d_in[1];
  const float* v  = (const float*)d_in[2];
  const float* Wq = (const float*)d_in[3];
  const float* bq = (const float*)d_in[4];
  const float* Wk = (const float*)d_in[5];
  const float* bk = (const float*)d_in[6];
  const float* Wv = (const float*)d_in[7];
  const float* bv = (const float*)d_in[8];
  const float* Wo = (const float*)d_in[9];
  const float* bo = (const float*)d_in[10];

  const size_t NE = NE_C, WE = WE_C;

  unsigned short* ws16 = (unsigned short*)d_ws;
  unsigned short* Wq_b = ws16;
  unsigned short* Wk_b = Wq_b + WE;
  unsigned short* Wv_b = Wk_b + WE;
  unsigned short* Wo_b = Wv_b + WE;
  unsigned short* Qb   = Wo_b + WE;
  unsigned short* Kb   = Qb + NE;
  unsigned short* Vb   = Kb + NE;
  unsigned short* X2   = Vb + NE;
  unsigned short* Qin  = X2 + NE;
  unsigned short* Kin  = Qin + NE;
  unsigned short* Vin  = Kin + NE;

  float* outMain = (float*)d_out;
  float* attnOut = outMain + (size_t)GM * GN;

  const int cvt_blocks = (int)((3 * NE + 4 * WE) / 8 / 256);   // 57344
  cvt_all<<<cvt_blocks, 256, 0, stream>>>(q, k, v, Wq, Wk, Wv, Wo,
                                          Qin, Kin, Vin, Wq_b, Wk_b, Wv_b, Wo_b);

  // merged Q/K/V projection: 3 x 512 blocks in one dispatch
  gemm_d<false, true><<<1536, 512, 0, stream>>>(
      Qin, Kin, Vin, Wq_b, Wk_b, Wv_b, bq, bk, bv, Qb, Kb, Vb);

  attn_kernel<<<GM, 256, 0, stream>>>(Qb, Kb, Vb, attnOut, X2);

  // output projection (fp32 out)
  gemm_d<true, false><<<512, 512, 0, stream>>>(
      X2, nullptr, nullptr, Wo_b, nullptr, nullptr, bo, nullptr, nullptr,
      outMain, nullptr, nullptr);
}